// Round 1
// baseline (1412.870 us; speedup 1.0000x reference)
//
#include <hip/hip_runtime.h>
#include <cstdint>

#define HID  4096
#define NHD  16
#define HDIM 256
#define SEQ  1024
#define BB   4
#define N3   12288
#define TOK  4096

typedef unsigned short u16;
typedef __bf16 bf16x8 __attribute__((ext_vector_type(8)));
typedef float  f32x4  __attribute__((ext_vector_type(4)));

__device__ __forceinline__ u16 f2b(float f) {
    unsigned u = __builtin_bit_cast(unsigned, f);
    u += 0x7fffu + ((u >> 16) & 1u);          // RNE
    return (u16)(u >> 16);
}
__device__ __forceinline__ float b2f(u16 v) {
    unsigned u = ((unsigned)v) << 16;
    return __builtin_bit_cast(float, u);
}

typedef __attribute__((address_space(3))) unsigned       lds_u32;
typedef const __attribute__((address_space(1))) unsigned glb_u32;
__device__ __forceinline__ void async16(const void* g, void* l) {
    __builtin_amdgcn_global_load_lds((glb_u32*)g, (lds_u32*)l, 16, 0, 0);
}

// ---------------- cast fp32 -> bf16 (row-major) ----------------
__global__ __launch_bounds__(256) void cast_bf16(const float4* __restrict__ in,
                                                 uint4* __restrict__ out, int n8) {
    int i = blockIdx.x * 256 + threadIdx.x;
    if (i >= n8) return;
    float4 a = in[2 * i], b = in[2 * i + 1];
    union { u16 h[8]; uint4 v; } o;
    o.h[0] = f2b(a.x); o.h[1] = f2b(a.y); o.h[2] = f2b(a.z); o.h[3] = f2b(a.w);
    o.h[4] = f2b(b.x); o.h[5] = f2b(b.y); o.h[6] = f2b(b.z); o.h[7] = f2b(b.w);
    out[i] = o.v;
}

// ---------------- transpose-cast: in[R][C] fp32 -> out[C][R] bf16 ----------------
__global__ __launch_bounds__(256) void tcast(const float* __restrict__ in,
                                             u16* __restrict__ out, int R, int C) {
    __shared__ u16 sT[64 * 80];
    const int c0 = blockIdx.x * 64, r0 = blockIdx.y * 64;
    const int t = threadIdx.x;
    const int rr = t >> 4, cc = (t & 15) * 4;
    for (int rnd = 0; rnd < 4; rnd++) {
        int r = rnd * 16 + rr;
        float4 v = *(const float4*)(in + (size_t)(r0 + r) * C + c0 + cc);
        sT[(cc + 0) * 80 + r] = f2b(v.x);
        sT[(cc + 1) * 80 + r] = f2b(v.y);
        sT[(cc + 2) * 80 + r] = f2b(v.z);
        sT[(cc + 3) * 80 + r] = f2b(v.w);
    }
    __syncthreads();
    const int orow = t >> 2, oc = (t & 3) * 16;
    u16* dst = out + (size_t)(c0 + orow) * R + r0 + oc;
    *(uint4*)dst       = *(uint4*)&sT[orow * 80 + oc];
    *(uint4*)(dst + 8) = *(uint4*)&sT[orow * 80 + oc + 8];
}

// ---------------- bf16 GEMM: C[M][N] = A[M][K] * Bt[N][K]^T ----------------
// 128x128 tile, BK=32, 4 waves (2x2), 16x16x32 MFMA, global_load_lds staging.
template <bool OUT_BF16>
__global__ __launch_bounds__(256) void gemm_bt(const u16* __restrict__ A,
                                               const u16* __restrict__ Bt,
                                               void* __restrict__ Cout,
                                               int M, int N, int K) {
    __shared__ u16 sA[4096];   // [128][32]
    __shared__ u16 sB[4096];   // [128][32]
    const int t = threadIdx.x;
    const int lane = t & 63, w = t >> 6;
    const int wm = w >> 1, wn = w & 1;
    const int m0 = blockIdx.y * 128, n0 = blockIdx.x * 128;
    const int ra = t >> 2, cb = (t & 3) * 8;
    const u16* gA = A + (size_t)(m0 + ra) * K + cb;
    const u16* gB = Bt + (size_t)(n0 + ra) * K + cb;
    const size_t rstep = (size_t)64 * K;
    u16* lA = &sA[t * 8];
    u16* lB = &sB[t * 8];
    const int fm = lane & 15, fk = (lane >> 4) * 8;
    f32x4 acc[4][4];
    const f32x4 z = {0.f, 0.f, 0.f, 0.f};
#pragma unroll
    for (int i = 0; i < 4; i++)
#pragma unroll
        for (int j = 0; j < 4; j++) acc[i][j] = z;

    const int nk = K >> 5;
    for (int kt = 0; kt < nk; kt++) {
        const int ko = kt * 32;
        async16(gA + ko, lA);
        async16(gA + ko + rstep, lA + 2048);
        async16(gB + ko, lB);
        async16(gB + ko + rstep, lB + 2048);
        asm volatile("s_waitcnt vmcnt(0)" ::: "memory");
        __syncthreads();
        bf16x8 af[4], bfr[4];
#pragma unroll
        for (int i = 0; i < 4; i++) {
            af[i]  = *(const bf16x8*)&sA[(wm * 64 + i * 16 + fm) * 32 + fk];
            bfr[i] = *(const bf16x8*)&sB[(wn * 64 + i * 16 + fm) * 32 + fk];
        }
#pragma unroll
        for (int i = 0; i < 4; i++)
#pragma unroll
            for (int j = 0; j < 4; j++)
                acc[i][j] = __builtin_amdgcn_mfma_f32_16x16x32_bf16(af[i], bfr[j], acc[i][j], 0, 0, 0);
        __syncthreads();
    }
    const int cr = (lane >> 4) * 4;
#pragma unroll
    for (int i = 0; i < 4; i++)
#pragma unroll
        for (int j = 0; j < 4; j++)
#pragma unroll
            for (int r = 0; r < 4; r++) {
                size_t row = (size_t)(m0 + wm * 64 + i * 16 + cr + r);
                size_t col = (size_t)(n0 + wn * 64 + j * 16 + fm);
                float v = acc[i][j][r];
                if (OUT_BF16) ((u16*)Cout)[row * N + col] = f2b(v);
                else          ((float*)Cout)[row * N + col] = v;
            }
}

// ---------------- RoPE + relayout ----------------
// qkv bf16 [tok][12288] -> Q,K [b][h][s][256] bf16 (rope applied), VT [b][h][256][s] bf16
__global__ __launch_bounds__(256) void rope_relayout(const int* __restrict__ pos_ids,
                                                     const u16* __restrict__ qkv,
                                                     u16* __restrict__ Qo,
                                                     u16* __restrict__ Ko,
                                                     u16* __restrict__ VTo) {
    __shared__ u16 sV[64 * 256];
    const int st = blockIdx.x, h = blockIdx.y, b = blockIdx.z;
    const int t = threadIdx.x;
    const int sbase = st * 64;

    // async V tile load directly to LDS (contiguous lane order == [tok][d] layout)
    {
        const u16* vbase = qkv + (size_t)(b * SEQ + sbase) * N3 + 2 * HID + h * HDIM;
        const int dcol = (t & 31) * 8;
        const int tokoff = t >> 5;
#pragma unroll
        for (int r = 0; r < 4; r++)
#pragma unroll
            for (int s8 = 0; s8 < 8; s8++) {
                int tok = r * 16 + s8 * 2 + tokoff;
                async16(vbase + (size_t)tok * N3 + dcol, &sV[r * 4096 + s8 * 512 + t * 8]);
            }
    }

    // q/k rope: wave = part (0:q-rot, 1:q-pass, 2:k-rot, 3:k-pass), lane = token
    const int tok = t & 63, part = t >> 6;
    const int s = sbase + tok;
    const int pos = pos_ids[b * SEQ + s];
    const int isK = part >> 1, isPass = part & 1;
    const u16* src = qkv + (size_t)(b * SEQ + s) * N3 + isK * HID + h * HDIM + isPass * 128;
    u16* dst = (isK ? Ko : Qo) + ((size_t)((b * NHD + h) * SEQ + s)) * HDIM + isPass * 128;
    if (!isPass) {
        const float fpos = (float)pos;
#pragma unroll
        for (int c = 0; c < 8; c++) {
            bf16x8 xa = *(const bf16x8*)(src + c * 8);
            bf16x8 xb = *(const bf16x8*)(src + 64 + c * 8);
            union { u16 h[8]; uint4 v; } o1, o2;
#pragma unroll
            for (int j = 0; j < 8; j++) {
                int i = c * 8 + j;
                // inv_freq = 10000^(-i/64) = exp(-i * ln(10000)/64)
                float invf = __expf((float)i * -0.14391156831212787f);
                float ang = fpos * invf;
                float sn, cs;
                __sincosf(ang, &sn, &cs);
                float x1 = (float)xa[j], x2 = (float)xb[j];
                o1.h[j] = f2b(x1 * cs - x2 * sn);
                o2.h[j] = f2b(x2 * cs + x1 * sn);
            }
            *(uint4*)(dst + c * 8)      = o1.v;
            *(uint4*)(dst + 64 + c * 8) = o2.v;
        }
    } else {
        const uint4* s4 = (const uint4*)src;
        uint4* d4 = (uint4*)dst;
#pragma unroll
        for (int c = 0; c < 16; c++) d4[c] = s4[c];
    }

    asm volatile("s_waitcnt vmcnt(0)" ::: "memory");
    __syncthreads();

    // VT out: thread t owns d-row t, 64 s-values -> 128B contiguous store
    u16* vt = VTo + ((size_t)((b * NHD + h) * HDIM + t)) * SEQ + sbase;
#pragma unroll
    for (int g = 0; g < 8; g++) {
        union { u16 h[8]; uint4 v; } o;
#pragma unroll
        for (int j = 0; j < 8; j++) o.h[j] = sV[(g * 8 + j) * 256 + t];
        *(uint4*)(vt + g * 8) = o.v;
    }
}

// ---------------- flash attention (causal), per (b,h,64-row q-tile) ----------------
__global__ __launch_bounds__(256) void attn_fwd(const u16* __restrict__ Q,
                                                const u16* __restrict__ K,
                                                const u16* __restrict__ VT,
                                                u16* __restrict__ attnO) {
    __shared__ u16 sK[32 * 256];   // [key][d]
    __shared__ u16 sVT[256 * 32];  // [d][key]
    __shared__ u16 sP[4 * 16 * 32];
    const int qt = (int)gridDim.x - 1 - (int)blockIdx.x;  // heavy tiles first
    const int h = blockIdx.y, b = blockIdx.z;
    const int t = threadIdx.x, lane = t & 63, w = t >> 6;
    const int fm = lane & 15, fk = (lane >> 4) * 8;
    const int qbase = qt * 64;
    const size_t head = ((size_t)(b * NHD + h)) * SEQ * HDIM;
    const u16* qptr = Q + head + (size_t)(qbase + w * 16 + fm) * HDIM;
    bf16x8 qf[8];
#pragma unroll
    for (int kk = 0; kk < 8; kk++) qf[kk] = *(const bf16x8*)(qptr + kk * 32 + fk);
    const f32x4 z = {0.f, 0.f, 0.f, 0.f};
    f32x4 O[16];
#pragma unroll
    for (int n = 0; n < 16; n++) O[n] = z;
    float mrow[4] = {-1e30f, -1e30f, -1e30f, -1e30f};
    float lrow[4] = {0.f, 0.f, 0.f, 0.f};
    const int nkt = qt * 2 + 2;
    const u16* kbaseP = K + head;
    const u16* vtbase = VT + head;
    const int qg_base = qbase + w * 16 + (lane >> 4) * 4;

    for (int kb = 0; kb < nkt; kb++) {
        {
            const int row = t >> 5, dcol = (t & 31) * 8;
#pragma unroll
            for (int r = 0; r < 4; r++)
                async16(kbaseP + (size_t)(kb * 32 + r * 8 + row) * HDIM + dcol,
                        &sK[r * 2048 + t * 8]);
            const int drow = t >> 2, scol = (t & 3) * 8;
#pragma unroll
            for (int r = 0; r < 4; r++)
                async16(vtbase + (size_t)(r * 64 + drow) * SEQ + kb * 32 + scol,
                        &sVT[r * 2048 + t * 8]);
        }
        asm volatile("s_waitcnt vmcnt(0)" ::: "memory");
        __syncthreads();

        f32x4 sc0 = z, sc1 = z;
#pragma unroll
        for (int kk = 0; kk < 8; kk++) {
            bf16x8 kf0 = *(const bf16x8*)&sK[fm * 256 + kk * 32 + fk];
            bf16x8 kf1 = *(const bf16x8*)&sK[(16 + fm) * 256 + kk * 32 + fk];
            sc0 = __builtin_amdgcn_mfma_f32_16x16x32_bf16(qf[kk], kf0, sc0, 0, 0, 0);
            sc1 = __builtin_amdgcn_mfma_f32_16x16x32_bf16(qf[kk], kf1, sc1, 0, 0, 0);
        }
        const int kg0 = kb * 32 + fm, kg1 = kg0 + 16;
        float alpha[4];
#pragma unroll
        for (int j = 0; j < 4; j++) {
            const int qg = qg_base + j;
            float s0 = (kg0 <= qg) ? sc0[j] * 0.0625f : -1e30f;
            float s1 = (kg1 <= qg) ? sc1[j] * 0.0625f : -1e30f;
            float mx = fmaxf(s0, s1);
            mx = fmaxf(mx, __shfl_xor(mx, 1, 64));
            mx = fmaxf(mx, __shfl_xor(mx, 2, 64));
            mx = fmaxf(mx, __shfl_xor(mx, 4, 64));
            mx = fmaxf(mx, __shfl_xor(mx, 8, 64));
            const float mn = fmaxf(mrow[j], mx);
            alpha[j] = __expf(mrow[j] - mn);
            mrow[j] = mn;
            float p0 = __expf(s0 - mn);
            float p1 = __expf(s1 - mn);
            float rs = p0 + p1;
            rs += __shfl_xor(rs, 1, 64);
            rs += __shfl_xor(rs, 2, 64);
            rs += __shfl_xor(rs, 4, 64);
            rs += __shfl_xor(rs, 8, 64);
            lrow[j] = lrow[j] * alpha[j] + rs;
            const int r = (lane >> 4) * 4 + j;
            sP[w * 512 + r * 32 + fm]      = f2b(p0);
            sP[w * 512 + r * 32 + 16 + fm] = f2b(p1);
        }
#pragma unroll
        for (int n = 0; n < 16; n++) {
            O[n][0] *= alpha[0]; O[n][1] *= alpha[1];
            O[n][2] *= alpha[2]; O[n][3] *= alpha[3];
        }
        bf16x8 pf = *(const bf16x8*)&sP[w * 512 + fm * 32 + fk];
#pragma unroll
        for (int n = 0; n < 16; n++) {
            bf16x8 vf = *(const bf16x8*)&sVT[(n * 16 + fm) * 32 + fk];
            O[n] = __builtin_amdgcn_mfma_f32_16x16x32_bf16(pf, vf, O[n], 0, 0, 0);
        }
        __syncthreads();
    }
#pragma unroll
    for (int j = 0; j < 4; j++) {
        const int r = (lane >> 4) * 4 + j;
        const float inv = 1.0f / lrow[j];
        u16* orow = attnO + (size_t)(b * SEQ + qbase + w * 16 + r) * HID + h * HDIM;
#pragma unroll
        for (int n = 0; n < 16; n++)
            orow[n * 16 + fm] = f2b(O[n][j] * inv);
    }
}

// ---------------- launch ----------------
extern "C" void kernel_launch(void* const* d_in, const int* in_sizes, int n_in,
                              void* d_out, int out_size, void* d_ws, size_t ws_size,
                              hipStream_t stream) {
    (void)in_sizes; (void)n_in; (void)out_size; (void)ws_size;
    const int*   pos    = (const int*)d_in[0];
    const float* hidden = (const float*)d_in[1];
    const float* wqkv   = (const float*)d_in[2];
    const float* wout   = (const float*)d_in[3];
    float* out = (float*)d_out;
    char* ws = (char*)d_ws;

    // workspace layout (256 MB total, aliased):
    u16* hiddenB = (u16*)ws;                              //  33,554,432 B
    u16* wqkvT   = (u16*)(ws + (size_t)33554432);         // 100,663,296 B
    u16* woutT   = (u16*)(ws + (size_t)134217728);        //  33,554,432 B
    u16* qkv     = (u16*)(ws + (size_t)167772160);        // 100,663,296 B
    // aliases (regions dead after their producers are consumed):
    u16* Qb    = wqkvT;                 // after GEMM1, wqkvT is dead
    u16* Kb    = wqkvT + 16777216;
    u16* VTb   = wqkvT + 33554432;
    u16* attnB = qkv;                   // after rope, qkv is dead

    cast_bf16<<<dim3(TOK * HID / 8 / 256), 256, 0, stream>>>(
        (const float4*)hidden, (uint4*)hiddenB, TOK * HID / 8);
    tcast<<<dim3(N3 / 64, HID / 64), 256, 0, stream>>>(wqkv, wqkvT, HID, N3);
    tcast<<<dim3(HID / 64, HID / 64), 256, 0, stream>>>(wout, woutT, HID, HID);
    gemm_bt<true><<<dim3(N3 / 128, TOK / 128), 256, 0, stream>>>(
        hiddenB, wqkvT, qkv, TOK, N3, HID);
    rope_relayout<<<dim3(SEQ / 64, NHD, BB), 256, 0, stream>>>(pos, qkv, Qb, Kb, VTb);
    attn_fwd<<<dim3(SEQ / 64, NHD, BB), 256, 0, stream>>>(Qb, Kb, VTb, attnB);
    gemm_bt<false><<<dim3(HID / 128, TOK / 128), 256, 0, stream>>>(
        attnB, woutT, out, TOK, HID, HID);
}

// Round 2
// 1393.036 us; speedup vs baseline: 1.0142x; 1.0142x over previous
//
#include <hip/hip_runtime.h>
#include <cstdint>

#define HID  4096
#define NHD  16
#define HDIM 256
#define SEQ  1024
#define BB   4
#define N3   12288
#define TOK  4096

typedef unsigned short u16;
typedef __bf16 bf16x8 __attribute__((ext_vector_type(8)));
typedef float  f32x4  __attribute__((ext_vector_type(4)));
typedef float  f32x16 __attribute__((ext_vector_type(16)));

__device__ __forceinline__ u16 f2b(float f) {
    unsigned u = __builtin_bit_cast(unsigned, f);
    u += 0x7fffu + ((u >> 16) & 1u);          // RNE
    return (u16)(u >> 16);
}
__device__ __forceinline__ float b2f(u16 v) {
    unsigned u = ((unsigned)v) << 16;
    return __builtin_bit_cast(float, u);
}

typedef __attribute__((address_space(3))) unsigned       lds_u32;
typedef const __attribute__((address_space(1))) unsigned glb_u32;
__device__ __forceinline__ void async16(const void* g, void* l) {
    __builtin_amdgcn_global_load_lds((glb_u32*)g, (lds_u32*)l, 16, 0, 0);
}

// ---------------- cast fp32 -> bf16 (row-major) ----------------
__global__ __launch_bounds__(256) void cast_bf16(const float4* __restrict__ in,
                                                 uint4* __restrict__ out, int n8) {
    int i = blockIdx.x * 256 + threadIdx.x;
    if (i >= n8) return;
    float4 a = in[2 * i], b = in[2 * i + 1];
    union { u16 h[8]; uint4 v; } o;
    o.h[0] = f2b(a.x); o.h[1] = f2b(a.y); o.h[2] = f2b(a.z); o.h[3] = f2b(a.w);
    o.h[4] = f2b(b.x); o.h[5] = f2b(b.y); o.h[6] = f2b(b.z); o.h[7] = f2b(b.w);
    out[i] = o.v;
}

// ---------------- transpose-cast: in[R][C] fp32 -> out[C][R] bf16 ----------------
__global__ __launch_bounds__(256) void tcast(const float* __restrict__ in,
                                             u16* __restrict__ out, int R, int C) {
    __shared__ u16 sT[64 * 80];
    const int c0 = blockIdx.x * 64, r0 = blockIdx.y * 64;
    const int t = threadIdx.x;
    const int rr = t >> 4, cc = (t & 15) * 4;
    for (int rnd = 0; rnd < 4; rnd++) {
        int r = rnd * 16 + rr;
        float4 v = *(const float4*)(in + (size_t)(r0 + r) * C + c0 + cc);
        sT[(cc + 0) * 80 + r] = f2b(v.x);
        sT[(cc + 1) * 80 + r] = f2b(v.y);
        sT[(cc + 2) * 80 + r] = f2b(v.z);
        sT[(cc + 3) * 80 + r] = f2b(v.w);
    }
    __syncthreads();
    const int orow = t >> 2, oc = (t & 3) * 16;
    u16* dst = out + (size_t)(c0 + orow) * R + r0 + oc;
    *(uint4*)dst       = *(uint4*)&sT[orow * 80 + oc];
    *(uint4*)(dst + 8) = *(uint4*)&sT[orow * 80 + oc + 8];
}

// ---------------- bf16 GEMM: C[M][N] = A[M][K] * Bt[N][K]^T ----------------
// 128x128 tile, BK=32, 4 waves (2x2), 32x32x16 MFMA, global_load_lds staging
// with XOR-swizzled columns for conflict-free fragment ds_read_b128.
// Grid: x = M/128 (fast, shares B-tile in L2), y = N/128.
template <bool OUT_BF16>
__global__ __launch_bounds__(256) void gemm_bt(const u16* __restrict__ A,
                                               const u16* __restrict__ Bt,
                                               void* __restrict__ Cout,
                                               int M, int N, int K) {
    __shared__ u16 sA[4096];   // [128][32], column-chunks xor-swizzled by (row&3)
    __shared__ u16 sB[4096];
    const int t = threadIdx.x;
    const int lane = t & 63, w = t >> 6;
    const int wm = w >> 1, wn = w & 1;
    const int m0 = blockIdx.x * 128, n0 = blockIdx.y * 128;
    const int ra = t >> 2;
    const int csw = (((t & 3) ^ (ra & 3))) * 8;   // swizzled column chunk
    const u16* gA = A + (size_t)(m0 + ra) * K + csw;
    const u16* gB = Bt + (size_t)(n0 + ra) * K + csw;
    const size_t rstep = (size_t)64 * K;
    u16* lA = &sA[t * 8];
    u16* lB = &sB[t * 8];
    const int ml = lane & 31, hh = lane >> 5;
    f32x16 acc[2][2];
#pragma unroll
    for (int i = 0; i < 2; i++)
#pragma unroll
        for (int j = 0; j < 2; j++)
#pragma unroll
            for (int r = 0; r < 16; r++) acc[i][j][r] = 0.f;

    const int nk = K >> 5;
    for (int kt = 0; kt < nk; kt++) {
        const int ko = kt * 32;
        async16(gA + ko, lA);
        async16(gA + ko + rstep, lA + 2048);
        async16(gB + ko, lB);
        async16(gB + ko + rstep, lB + 2048);
        asm volatile("s_waitcnt vmcnt(0)" ::: "memory");
        __syncthreads();
        bf16x8 a[2][2], b[2][2];
#pragma unroll
        for (int i = 0; i < 2; i++)
#pragma unroll
            for (int k0 = 0; k0 < 2; k0++) {
                const int chunk = (((hh + 2 * k0) ^ (ml & 3))) * 8;
                a[i][k0] = *(const bf16x8*)&sA[(wm * 64 + i * 32 + ml) * 32 + chunk];
                b[i][k0] = *(const bf16x8*)&sB[(wn * 64 + i * 32 + ml) * 32 + chunk];
            }
#pragma unroll
        for (int k0 = 0; k0 < 2; k0++)
#pragma unroll
            for (int i = 0; i < 2; i++)
#pragma unroll
                for (int j = 0; j < 2; j++)
                    acc[i][j] = __builtin_amdgcn_mfma_f32_32x32x16_bf16(
                        a[i][k0], b[j][k0], acc[i][j], 0, 0, 0);
        __syncthreads();
    }
    // C/D layout (32x32): col = lane&31, row = (r&3) + 8*(r>>2) + 4*(lane>>5)
#pragma unroll
    for (int i = 0; i < 2; i++)
#pragma unroll
        for (int j = 0; j < 2; j++)
#pragma unroll
            for (int r = 0; r < 16; r++) {
                size_t row = (size_t)(m0 + wm * 64 + i * 32 + (r & 3) + 8 * (r >> 2) + 4 * hh);
                size_t col = (size_t)(n0 + wn * 64 + j * 32 + ml);
                float v = acc[i][j][r];
                if (OUT_BF16) ((u16*)Cout)[row * N + col] = f2b(v);
                else          ((float*)Cout)[row * N + col] = v;
            }
}

// ---------------- RoPE + relayout ----------------
// qkv bf16 [tok][12288] -> Q,K [b][h][s][256] bf16 (rope applied), VT [b][h][256][s] bf16
__global__ __launch_bounds__(256) void rope_relayout(const int* __restrict__ pos_ids,
                                                     const u16* __restrict__ qkv,
                                                     u16* __restrict__ Qo,
                                                     u16* __restrict__ Ko,
                                                     u16* __restrict__ VTo) {
    __shared__ u16 sV[64 * 256];
    const int st = blockIdx.x, h = blockIdx.y, b = blockIdx.z;
    const int t = threadIdx.x;
    const int sbase = st * 64;

    {
        const u16* vbase = qkv + (size_t)(b * SEQ + sbase) * N3 + 2 * HID + h * HDIM;
        const int dcol = (t & 31) * 8;
        const int tokoff = t >> 5;
#pragma unroll
        for (int r = 0; r < 4; r++)
#pragma unroll
            for (int s8 = 0; s8 < 8; s8++) {
                int tok = r * 16 + s8 * 2 + tokoff;
                async16(vbase + (size_t)tok * N3 + dcol, &sV[r * 4096 + s8 * 512 + t * 8]);
            }
    }

    const int tok = t & 63, part = t >> 6;
    const int s = sbase + tok;
    const int pos = pos_ids[b * SEQ + s];
    const int isK = part >> 1, isPass = part & 1;
    const u16* src = qkv + (size_t)(b * SEQ + s) * N3 + isK * HID + h * HDIM + isPass * 128;
    u16* dst = (isK ? Ko : Qo) + ((size_t)((b * NHD + h) * SEQ + s)) * HDIM + isPass * 128;
    if (!isPass) {
        const float fpos = (float)pos;
#pragma unroll
        for (int c = 0; c < 8; c++) {
            bf16x8 xa = *(const bf16x8*)(src + c * 8);
            bf16x8 xb = *(const bf16x8*)(src + 64 + c * 8);
            union { u16 h[8]; uint4 v; } o1, o2;
#pragma unroll
            for (int j = 0; j < 8; j++) {
                int i = c * 8 + j;
                float invf = __expf((float)i * -0.14391156831212787f);
                float ang = fpos * invf;
                float sn, cs;
                __sincosf(ang, &sn, &cs);
                float x1 = (float)xa[j], x2 = (float)xb[j];
                o1.h[j] = f2b(x1 * cs - x2 * sn);
                o2.h[j] = f2b(x2 * cs + x1 * sn);
            }
            *(uint4*)(dst + c * 8)      = o1.v;
            *(uint4*)(dst + 64 + c * 8) = o2.v;
        }
    } else {
        const uint4* s4 = (const uint4*)src;
        uint4* d4 = (uint4*)dst;
#pragma unroll
        for (int c = 0; c < 16; c++) d4[c] = s4[c];
    }

    asm volatile("s_waitcnt vmcnt(0)" ::: "memory");
    __syncthreads();

    u16* vt = VTo + ((size_t)((b * NHD + h) * HDIM + t)) * SEQ + sbase;
#pragma unroll
    for (int g = 0; g < 8; g++) {
        union { u16 h[8]; uint4 v; } o;
#pragma unroll
        for (int j = 0; j < 8; j++) o.h[j] = sV[(g * 8 + j) * 256 + t];
        *(uint4*)(vt + g * 8) = o.v;
    }
}

// ---------------- flash attention (causal), per (b,h,64-row q-tile) ----------------
// sK [32 key][256 d] with column-chunks xor-swizzled by (key&7);
// sVT [256 d][32 s] with s-chunks xor-swizzled by (d&3).
__global__ __launch_bounds__(256) void attn_fwd(const u16* __restrict__ Q,
                                                const u16* __restrict__ K,
                                                const u16* __restrict__ VT,
                                                u16* __restrict__ attnO) {
    __shared__ u16 sK[32 * 256];
    __shared__ u16 sVT[256 * 32];
    __shared__ u16 sP[4 * 16 * 32];
    const int qt = (int)gridDim.x - 1 - (int)blockIdx.x;  // heavy tiles first
    const int h = blockIdx.y, b = blockIdx.z;
    const int t = threadIdx.x, lane = t & 63, w = t >> 6;
    const int fm = lane & 15, g = lane >> 4, fk = g * 8;
    const int qbase = qt * 64;
    const size_t head = ((size_t)(b * NHD + h)) * SEQ * HDIM;
    const u16* qptr = Q + head + (size_t)(qbase + w * 16 + fm) * HDIM;
    bf16x8 qf[8];
#pragma unroll
    for (int kk = 0; kk < 8; kk++) qf[kk] = *(const bf16x8*)(qptr + kk * 32 + fk);
    const f32x4 z = {0.f, 0.f, 0.f, 0.f};
    f32x4 O[16];
#pragma unroll
    for (int n = 0; n < 16; n++) O[n] = z;
    float mrow[4] = {-1e30f, -1e30f, -1e30f, -1e30f};
    float lrow[4] = {0.f, 0.f, 0.f, 0.f};
    const int nkt = qt * 2 + 2;
    const u16* kbaseP = K + head;
    const u16* vtbase = VT + head;
    const int qg_base = qbase + w * 16 + g * 4;

    for (int kb = 0; kb < nkt; kb++) {
        {
            const int krow = t >> 5;                            // key row within 8
            const int dcol = ((t & 31) ^ krow) * 8;             // swizzle by key&7
#pragma unroll
            for (int r = 0; r < 4; r++)
                async16(kbaseP + (size_t)(kb * 32 + r * 8 + krow) * HDIM + dcol,
                        &sK[r * 2048 + t * 8]);
            const int drow = t >> 2;
            const int scol = (((t & 3) ^ (drow & 3))) * 8;      // swizzle by d&3
#pragma unroll
            for (int r = 0; r < 4; r++)
                async16(vtbase + (size_t)(r * 64 + drow) * SEQ + kb * 32 + scol,
                        &sVT[r * 2048 + t * 8]);
        }
        asm volatile("s_waitcnt vmcnt(0)" ::: "memory");
        __syncthreads();

        f32x4 sc0 = z, sc1 = z;
#pragma unroll
        for (int kk = 0; kk < 8; kk++) {
            const int p = ((kk * 4 + g) ^ (fm & 7)) * 8;
            bf16x8 kf0 = *(const bf16x8*)&sK[fm * 256 + p];
            bf16x8 kf1 = *(const bf16x8*)&sK[(16 + fm) * 256 + p];
            sc0 = __builtin_amdgcn_mfma_f32_16x16x32_bf16(qf[kk], kf0, sc0, 0, 0, 0);
            sc1 = __builtin_amdgcn_mfma_f32_16x16x32_bf16(qf[kk], kf1, sc1, 0, 0, 0);
        }
        const int kg0 = kb * 32 + fm, kg1 = kg0 + 16;
        float alpha[4];
#pragma unroll
        for (int j = 0; j < 4; j++) {
            const int qg = qg_base + j;
            float s0 = (kg0 <= qg) ? sc0[j] * 0.0625f : -1e30f;
            float s1 = (kg1 <= qg) ? sc1[j] * 0.0625f : -1e30f;
            float mx = fmaxf(s0, s1);
            mx = fmaxf(mx, __shfl_xor(mx, 1, 64));
            mx = fmaxf(mx, __shfl_xor(mx, 2, 64));
            mx = fmaxf(mx, __shfl_xor(mx, 4, 64));
            mx = fmaxf(mx, __shfl_xor(mx, 8, 64));
            const float mn = fmaxf(mrow[j], mx);
            alpha[j] = __expf(mrow[j] - mn);
            mrow[j] = mn;
            float p0 = __expf(s0 - mn);
            float p1 = __expf(s1 - mn);
            float rs = p0 + p1;
            rs += __shfl_xor(rs, 1, 64);
            rs += __shfl_xor(rs, 2, 64);
            rs += __shfl_xor(rs, 4, 64);
            rs += __shfl_xor(rs, 8, 64);
            lrow[j] = lrow[j] * alpha[j] + rs;
            const int r = g * 4 + j;
            sP[w * 512 + r * 32 + fm]      = f2b(p0);
            sP[w * 512 + r * 32 + 16 + fm] = f2b(p1);
        }
#pragma unroll
        for (int n = 0; n < 16; n++) {
            O[n][0] *= alpha[0]; O[n][1] *= alpha[1];
            O[n][2] *= alpha[2]; O[n][3] *= alpha[3];
        }
        bf16x8 pf = *(const bf16x8*)&sP[w * 512 + fm * 32 + fk];
#pragma unroll
        for (int n = 0; n < 16; n++) {
            const int d = n * 16 + fm;
            bf16x8 vf = *(const bf16x8*)&sVT[d * 32 + ((g ^ (fm & 3)) << 3)];
            O[n] = __builtin_amdgcn_mfma_f32_16x16x32_bf16(pf, vf, O[n], 0, 0, 0);
        }
        __syncthreads();
    }
#pragma unroll
    for (int j = 0; j < 4; j++) {
        const int r = g * 4 + j;
        const float inv = 1.0f / lrow[j];
        u16* orow = attnO + (size_t)(b * SEQ + qbase + w * 16 + r) * HID + h * HDIM;
#pragma unroll
        for (int n = 0; n < 16; n++)
            orow[n * 16 + fm] = f2b(O[n][j] * inv);
    }
}

// ---------------- launch ----------------
extern "C" void kernel_launch(void* const* d_in, const int* in_sizes, int n_in,
                              void* d_out, int out_size, void* d_ws, size_t ws_size,
                              hipStream_t stream) {
    (void)in_sizes; (void)n_in; (void)out_size; (void)ws_size;
    const int*   pos    = (const int*)d_in[0];
    const float* hidden = (const float*)d_in[1];
    const float* wqkv   = (const float*)d_in[2];
    const float* wout   = (const float*)d_in[3];
    float* out = (float*)d_out;
    char* ws = (char*)d_ws;

    u16* hiddenB = (u16*)ws;                              //  33,554,432 B
    u16* wqkvT   = (u16*)(ws + (size_t)33554432);         // 100,663,296 B
    u16* woutT   = (u16*)(ws + (size_t)134217728);        //  33,554,432 B
    u16* qkv     = (u16*)(ws + (size_t)167772160);        // 100,663,296 B
    u16* Qb    = wqkvT;                 // after GEMM1, wqkvT is dead
    u16* Kb    = wqkvT + 16777216;
    u16* VTb   = wqkvT + 33554432;
    u16* attnB = qkv;                   // after rope, qkv is dead

    cast_bf16<<<dim3(TOK * HID / 8 / 256), 256, 0, stream>>>(
        (const float4*)hidden, (uint4*)hiddenB, TOK * HID / 8);
    tcast<<<dim3(N3 / 64, HID / 64), 256, 0, stream>>>(wqkv, wqkvT, HID, N3);
    tcast<<<dim3(HID / 64, HID / 64), 256, 0, stream>>>(wout, woutT, HID, HID);
    gemm_bt<true><<<dim3(TOK / 128, N3 / 128), 256, 0, stream>>>(
        hiddenB, wqkvT, qkv, TOK, N3, HID);
    rope_relayout<<<dim3(SEQ / 64, NHD, BB), 256, 0, stream>>>(pos, qkv, Qb, Kb, VTb);
    attn_fwd<<<dim3(SEQ / 64, NHD, BB), 256, 0, stream>>>(Qb, Kb, VTb, attnB);
    gemm_bt<false><<<dim3(TOK / 128, HID / 128), 256, 0, stream>>>(
        attnB, woutT, out, TOK, HID, HID);
}